// Round 2
// baseline (396.371 us; speedup 1.0000x reference)
//
#include <hip/hip_runtime.h>
#include <math.h>

#define BB 4
#define TT 1024
#define FIN 256
#define DD 128
#define CL 16              // chunk length
#define NC 64              // chunks = TT/CL
#define ROWS (BB*TT)       // 4096
#define DDP (DD+4)         // padded LDS row stride (bank-conflict break)

// ---------------------------------------------------------------------------
// Kernel 1: LayerNorm + 4 GEMMs (K,Q with phi=elu+1; V plain; XS = xn@Ws^T+bs)
// grid 512 x 256 threads, 8 rows/block.
// ---------------------------------------------------------------------------
__global__ __launch_bounds__(256) void k_ln_qkv(
    const float* __restrict__ x, const float* __restrict__ gamma, const float* __restrict__ beta,
    const float* __restrict__ Wk, const float* __restrict__ Wq, const float* __restrict__ Wv,
    const float* __restrict__ Ws, const float* __restrict__ bs,
    float* __restrict__ Kp, float* __restrict__ Qp, float* __restrict__ Vp, float* __restrict__ XSp)
{
    __shared__ float xt[8][FIN];
    const int tid  = threadIdx.x;
    const int row0 = blockIdx.x * 8;

    {   // LayerNorm: 32 threads per row, 8 elements per thread
        const int r = tid >> 5, l = tid & 31;
        const float* xr = x + (size_t)(row0 + r) * FIN + l * 8;
        float v[8];
        #pragma unroll
        for (int k = 0; k < 8; ++k) v[k] = xr[k];
        float s = 0.f, sq = 0.f;
        #pragma unroll
        for (int k = 0; k < 8; ++k) { s += v[k]; sq += v[k] * v[k]; }
        #pragma unroll
        for (int m = 16; m >= 1; m >>= 1) {
            s  += __shfl_xor(s,  m, 64);
            sq += __shfl_xor(sq, m, 64);
        }
        const float mu  = s * (1.0f / FIN);
        const float var = sq * (1.0f / FIN) - mu * mu;
        const float rs  = rsqrtf(var + 1e-5f);
        #pragma unroll
        for (int k = 0; k < 8; ++k) {
            const int f = l * 8 + k;
            xt[r][f] = (v[k] - mu) * rs * gamma[f] + beta[f];
        }
    }
    __syncthreads();

    const int m0 = tid >> 7;            // 0 -> K, 1 -> Q
    const int d  = tid & 127;
    const int m1 = (tid + 256) >> 7;    // 2 -> V, 3 -> XS
    const float* W0  = (m0 == 0 ? Wk : Wq) + (size_t)d * FIN;
    const float* W1r = (m1 == 2 ? Wv : Ws) + (size_t)d * FIN;

    float acc0[8], acc1[8];
    #pragma unroll
    for (int r = 0; r < 8; ++r) { acc0[r] = 0.f; acc1[r] = 0.f; }

    for (int k4 = 0; k4 < FIN / 4; ++k4) {
        const float4 w0 = ((const float4*)W0)[k4];
        const float4 w1 = ((const float4*)W1r)[k4];
        #pragma unroll
        for (int r = 0; r < 8; ++r) {
            const float4 xv = ((const float4*)xt[r])[k4];   // broadcast read
            acc0[r] += w0.x * xv.x + w0.y * xv.y + w0.z * xv.z + w0.w * xv.w;
            acc1[r] += w1.x * xv.x + w1.y * xv.y + w1.z * xv.z + w1.w * xv.w;
        }
    }

    float* dst0 = (m0 == 0 ? Kp : Qp);
    float* dst1 = (m1 == 2 ? Vp : XSp);
    const float bsv = (m1 == 3) ? bs[d] : 0.f;
    #pragma unroll
    for (int r = 0; r < 8; ++r) {
        float a = acc0[r];
        a = (a > 0.f) ? (a + 1.f) : expf(a);          // phi = elu+1
        dst0[(size_t)(row0 + r) * DD + d] = a;
        dst1[(size_t)(row0 + r) * DD + d] = acc1[r] + bsv;
    }
}

// ---------------------------------------------------------------------------
// Kernel 2: per-chunk sums  sumKV[b,c,i,j] = sum_t K[t,i]V[t,j], sumK[b,c,i]
// grid 256 (b*c) x 256 threads
// ---------------------------------------------------------------------------
__global__ __launch_bounds__(256) void k_chunksum(
    const float* __restrict__ Kp, const float* __restrict__ Vp,
    float* __restrict__ SKV, float* __restrict__ SK)
{
    __shared__ float Kb[CL][DD];
    __shared__ float Vb[CL][DD];
    const int tid = threadIdx.x;
    const int c = blockIdx.x & (NC - 1);
    const int b = blockIdx.x >> 6;
    const size_t base = (size_t)(b * TT + c * CL) * DD;

    #pragma unroll
    for (int q = 0; q < 2; ++q) {
        const int fi = q * 256 + tid;
        ((float4*)&Kb[0][0])[fi] = ((const float4*)(Kp + base))[fi];
        ((float4*)&Vb[0][0])[fi] = ((const float4*)(Vp + base))[fi];
    }
    __syncthreads();

    const int j = tid & 127, hi = tid >> 7;
    float acc[64];
    #pragma unroll
    for (int w = 0; w < 64; ++w) acc[w] = 0.f;

    for (int t = 0; t < CL; ++t) {
        const float vj = Vb[t][j];
        #pragma unroll
        for (int w4 = 0; w4 < 16; ++w4) {
            const float4 kf = *(const float4*)&Kb[t][hi * 64 + w4 * 4];
            acc[w4 * 4 + 0] += kf.x * vj;
            acc[w4 * 4 + 1] += kf.y * vj;
            acc[w4 * 4 + 2] += kf.z * vj;
            acc[w4 * 4 + 3] += kf.w * vj;
        }
    }

    float* out = SKV + (size_t)(b * NC + c) * DD * DD;
    #pragma unroll
    for (int w = 0; w < 64; ++w) {
        const int i = hi * 64 + w;
        out[(size_t)i * DD + j] = acc[w];
    }
    if (tid < DD) {
        float s = 0.f;
        #pragma unroll
        for (int t = 0; t < CL; ++t) s += Kb[t][tid];
        SK[(size_t)(b * NC + c) * DD + tid] = s;
    }
}

// ---------------------------------------------------------------------------
// Kernel 3: prefix over chunks -> chunk-END slices of S and Z. Unroll-4 with
// explicit prefetch to pipeline the 64-step dependent chain.
// ---------------------------------------------------------------------------
__global__ __launch_bounds__(256) void k_prefix(
    const float* __restrict__ SKV, const float* __restrict__ SK,
    const float* __restrict__ S0, const float* __restrict__ Z0,
    float* __restrict__ Sout, float* __restrict__ Zout)
{
    const int gid = blockIdx.x * 256 + threadIdx.x;   // 0..65535
    const int b = gid >> 14, e = gid & 16383;
    float acc = S0[(size_t)b * 16384 + e];
    const float* p = SKV + (size_t)b * NC * 16384 + e;
    float* so = Sout + ((size_t)b * TT + CL - 1) * 16384 + e;

    float v0 = p[0], v1 = p[16384], v2 = p[2 * 16384], v3 = p[3 * 16384];
    for (int c4 = 0; c4 < 16; ++c4) {
        float n0 = 0.f, n1 = 0.f, n2 = 0.f, n3 = 0.f;
        if (c4 < 15) {
            const float* pn = p + (size_t)(c4 * 4 + 4) * 16384;
            n0 = pn[0]; n1 = pn[16384]; n2 = pn[2 * 16384]; n3 = pn[3 * 16384];
        }
        const float a0 = acc + v0, a1 = a0 + v1, a2 = a1 + v2, a3 = a2 + v3;
        float* s4 = so + (size_t)(c4 * 4) * CL * 16384;
        s4[0] = a0;
        s4[(size_t)CL * 16384]     = a1;
        s4[(size_t)2 * CL * 16384] = a2;
        s4[(size_t)3 * CL * 16384] = a3;
        acc = a3;
        v0 = n0; v1 = n1; v2 = n2; v3 = n3;
    }

    if (gid < BB * DD) {
        const int b2 = gid >> 7, i = gid & 127;
        float z = Z0[b2 * DD + i];
        for (int c = 0; c < NC; ++c) {
            z += SK[(size_t)(b2 * NC + c) * DD + i];
            Zout[(size_t)(b2 * TT + c * CL + CL - 1) * DD + i] = z;
        }
    }
}

// ---------------------------------------------------------------------------
// Kernel 4: barrier-free streaming S/Z writer. block = (b, chunk, col-half).
// State 128x64 in registers; t-loop has NO syncthreads and no reductions.
// grid 512 x 256 threads.
// ---------------------------------------------------------------------------
__global__ __launch_bounds__(256) void k_swrite(
    const float* __restrict__ Kp, const float* __restrict__ Vp,
    const float* __restrict__ S0, const float* __restrict__ Z0,
    float* Sout, float* Zout)
{
    __shared__ float Kb[CL][DD];
    __shared__ float Vb[CL][64];

    const int tid  = threadIdx.x;
    const int half = blockIdx.x & 1;
    const int c    = (blockIdx.x >> 1) & (NC - 1);
    const int b    = blockIdx.x >> 7;
    const int j0   = half * 64;
    const size_t rbase = (size_t)(b * TT + c * CL);

    {
        const float4* Ksrc = (const float4*)(Kp + rbase * DD);
        #pragma unroll
        for (int q = 0; q < 2; ++q) {
            const int fi = q * 256 + tid;
            ((float4*)&Kb[0][0])[fi] = Ksrc[fi];
        }
        const int tv = tid >> 4, gv = tid & 15;
        *(float4*)&Vb[tv][gv * 4] = *(const float4*)(Vp + (rbase + tv) * DD + j0 + gv * 4);
    }

    const int g = tid & 15, h = tid >> 4;   // i = w*16+h, j = j0+g*4
    float4 acc[8];
    {
        const float* src = (c == 0) ? (S0 + (size_t)b * 16384)
                                    : (Sout + (rbase - 1) * 16384);
        #pragma unroll
        for (int w = 0; w < 8; ++w) {
            const int i = w * 16 + h;
            acc[w] = *(const float4*)(src + (size_t)i * DD + j0 + g * 4);
        }
    }
    float zacc = 0.f;
    const bool doZ = (half == 0) && (tid < DD);
    if (doZ) {
        zacc = (c == 0) ? Z0[b * DD + tid]
                        : Zout[(rbase - 1) * DD + tid];
    }
    __syncthreads();

    #pragma unroll
    for (int t = 0; t < CL - 1; ++t) {
        const float4 v4 = *(const float4*)&Vb[t][g * 4];
        float* srow = Sout + (rbase + t) * 16384 + j0 + g * 4;
        #pragma unroll
        for (int w = 0; w < 8; ++w) {
            const int i = w * 16 + h;
            const float kk = Kb[t][i];
            acc[w].x += kk * v4.x; acc[w].y += kk * v4.y;
            acc[w].z += kk * v4.z; acc[w].w += kk * v4.w;
            *(float4*)(srow + (size_t)i * DD) = acc[w];
        }
        if (doZ) {
            zacc += Kb[t][tid];
            Zout[(rbase + t) * DD + tid] = zacc;
        }
    }
    // t = CL-1 row was already written by k_prefix; no update needed.
}

// ---------------------------------------------------------------------------
// Kernel 5: fused num/den + 2-layer MLP + residual. block = one chunk (16 rows).
// num[r] = Q[r].S_start + sum_{t'<=r} A[r][t'] V[t'],  A = Q K^T
// den[r] = Q[r].Z_start + sum_{t'<=r} A[r][t'] + eps
// grid 256 x 256 threads.
// ---------------------------------------------------------------------------
__global__ __launch_bounds__(256) void k_numden_mlp(
    const float* __restrict__ Kp, const float* __restrict__ Qp, const float* __restrict__ Vp,
    const float* __restrict__ XSp, const float* __restrict__ S0, const float* __restrict__ Z0,
    const float* __restrict__ Sout, const float* __restrict__ Zout,
    const float* __restrict__ W1, const float* __restrict__ b1,
    const float* __restrict__ W2, const float* __restrict__ b2,
    float* __restrict__ Oout)
{
    __shared__ float Qs[CL][DDP];   // padded: breaks row-stride-128 bank conflicts
    __shared__ float Ks[CL][DDP];
    __shared__ float Vs[CL][DD];
    __shared__ float As[CL][CL];
    __shared__ float Zs[DD];
    __shared__ float den[CL];
    __shared__ float h0[CL][DD];
    __shared__ float h1[CL][DD];
    __shared__ float parr[CL][256];

    const int tid = threadIdx.x;
    const int c = blockIdx.x & (NC - 1);
    const int b = blockIdx.x >> 6;
    const size_t rbase = (size_t)(b * TT + c * CL);

    {   // stage Q,K,V
        const float4* Qsrc = (const float4*)(Qp + rbase * DD);
        const float4* Ksrc = (const float4*)(Kp + rbase * DD);
        const float4* Vsrc = (const float4*)(Vp + rbase * DD);
        #pragma unroll
        for (int q = 0; q < 2; ++q) {
            const int fi = q * 256 + tid;
            const int row = fi >> 5, c4 = fi & 31;
            *(float4*)&Qs[row][c4 * 4] = Qsrc[fi];
            *(float4*)&Ks[row][c4 * 4] = Ksrc[fi];
            ((float4*)&Vs[0][0])[fi]   = Vsrc[fi];
        }
        if (tid < DD)
            Zs[tid] = (c == 0) ? Z0[b * DD + tid] : Zout[(rbase - 1) * DD + tid];
    }
    __syncthreads();

    {   // A[r][t'] (full 16x16; masked later)
        const int r = tid >> 4, t2 = tid & 15;
        float s = 0.f;
        #pragma unroll
        for (int k4 = 0; k4 < DD / 4; ++k4) {
            const float4 q4 = *(const float4*)&Qs[r][k4 * 4];
            const float4 k4v = *(const float4*)&Ks[t2][k4 * 4];
            s += q4.x * k4v.x + q4.y * k4v.y + q4.z * k4v.z + q4.w * k4v.w;
        }
        As[r][t2] = s;
    }
    __syncthreads();
    if (tid < CL) {
        const int r = tid;
        float s = 1e-5f;
        #pragma unroll
        for (int k = 0; k < DD; ++k) s += Qs[r][k] * Zs[k];
        #pragma unroll
        for (int t2 = 0; t2 < CL; ++t2) if (t2 <= r) s += As[r][t2];
        den[r] = s;
    }
    __syncthreads();

    {   // num: thread = (row r = tid>>4, j-octet)
        const int r = tid >> 4;
        const int jq = (tid & 15) * 8;
        float4 a0 = {0, 0, 0, 0}, a1 = {0, 0, 0, 0};
        const float* Sstart = (c == 0) ? (S0 + (size_t)b * 16384)
                                       : (Sout + (rbase - 1) * 16384);
        for (int i = 0; i < DD; ++i) {
            const float qv = Qs[r][i];
            const float4 s0v = *(const float4*)(Sstart + (size_t)i * DD + jq);
            const float4 s1v = *(const float4*)(Sstart + (size_t)i * DD + jq + 4);
            a0.x += qv * s0v.x; a0.y += qv * s0v.y; a0.z += qv * s0v.z; a0.w += qv * s0v.w;
            a1.x += qv * s1v.x; a1.y += qv * s1v.y; a1.z += qv * s1v.z; a1.w += qv * s1v.w;
        }
        #pragma unroll
        for (int t2 = 0; t2 < CL; ++t2) {
            const float av = (t2 <= r) ? As[r][t2] : 0.f;
            const float4 v0 = *(const float4*)&Vs[t2][jq];
            const float4 v1 = *(const float4*)&Vs[t2][jq + 4];
            a0.x += av * v0.x; a0.y += av * v0.y; a0.z += av * v0.z; a0.w += av * v0.w;
            a1.x += av * v1.x; a1.y += av * v1.y; a1.z += av * v1.z; a1.w += av * v1.w;
        }
        const float rd = 1.0f / den[r];
        a0.x *= rd; a0.y *= rd; a0.z *= rd; a0.w *= rd;
        a1.x *= rd; a1.y *= rd; a1.z *= rd; a1.w *= rd;
        *(float4*)&h0[r][jq]     = a0;
        *(float4*)&h0[r][jq + 4] = a1;
    }
    __syncthreads();

    const int d = tid & 127, sh = tid >> 7;
    {   // MLP layer 1
        float4 w1r[16];
        #pragma unroll
        for (int k4 = 0; k4 < 16; ++k4)
            w1r[k4] = *(const float4*)(W1 + (size_t)d * DD + sh * 64 + k4 * 4);
        #pragma unroll
        for (int r = 0; r < CL; ++r) {
            float pp = 0.f;
            #pragma unroll
            for (int k4 = 0; k4 < 16; ++k4) {
                const float4 xv = *(const float4*)&h0[r][sh * 64 + k4 * 4];
                pp += w1r[k4].x * xv.x + w1r[k4].y * xv.y + w1r[k4].z * xv.z + w1r[k4].w * xv.w;
            }
            parr[r][tid] = pp;
        }
    }
    __syncthreads();
    #pragma unroll
    for (int q = 0; q < 8; ++q) {
        const int f = q * 256 + tid;
        const int r = f >> 7, dd2 = f & 127;
        h1[r][dd2] = fmaxf(parr[r][dd2] + parr[r][dd2 + 128] + b1[dd2], 0.f);
    }
    __syncthreads();
    {   // MLP layer 2
        float4 w2r[16];
        #pragma unroll
        for (int k4 = 0; k4 < 16; ++k4)
            w2r[k4] = *(const float4*)(W2 + (size_t)d * DD + sh * 64 + k4 * 4);
        #pragma unroll
        for (int r = 0; r < CL; ++r) {
            float pp = 0.f;
            #pragma unroll
            for (int k4 = 0; k4 < 16; ++k4) {
                const float4 xv = *(const float4*)&h1[r][sh * 64 + k4 * 4];
                pp += w2r[k4].x * xv.x + w2r[k4].y * xv.y + w2r[k4].z * xv.z + w2r[k4].w * xv.w;
            }
            parr[r][tid] = pp;
        }
    }
    __syncthreads();
    #pragma unroll
    for (int q = 0; q < 8; ++q) {
        const int f = q * 256 + tid;
        const int r = f >> 7, dd2 = f & 127;
        const float hv = fmaxf(parr[r][dd2] + parr[r][dd2 + 128] + b2[dd2], 0.f);
        Oout[rbase * DD + f] = hv + XSp[rbase * DD + f];
    }
}

// ---------------------------------------------------------------------------
extern "C" void kernel_launch(void* const* d_in, const int* in_sizes, int n_in,
                              void* d_out, int out_size, void* d_ws, size_t ws_size,
                              hipStream_t stream)
{
    const float* x  = (const float*)d_in[0];
    const float* S0 = (const float*)d_in[1];
    const float* Z0 = (const float*)d_in[2];
    const float* g  = (const float*)d_in[3];
    const float* be = (const float*)d_in[4];
    const float* Wk = (const float*)d_in[5];
    const float* Wq = (const float*)d_in[6];
    const float* Wv = (const float*)d_in[7];
    const float* W1 = (const float*)d_in[8];
    const float* b1 = (const float*)d_in[9];
    const float* W2 = (const float*)d_in[10];
    const float* b2 = (const float*)d_in[11];
    const float* Ws = (const float*)d_in[12];
    const float* bs = (const float*)d_in[13];

    float* outp = (float*)d_out;                    // [B,T,D]
    float* Sout = outp + (size_t)ROWS * DD;         // [B,T,D,D]
    float* Zout = Sout + (size_t)BB * TT * DD * DD; // [B,T,D]

    float* ws  = (float*)d_ws;
    float* Kp  = ws;
    float* Qp  = Kp + (size_t)ROWS * DD;
    float* Vp  = Qp + (size_t)ROWS * DD;
    float* XSp = Vp + (size_t)ROWS * DD;
    float* SKV = XSp + (size_t)ROWS * DD;
    float* SK  = SKV + (size_t)BB * NC * DD * DD;

    k_ln_qkv    <<<ROWS / 8, 256, 0, stream>>>(x, g, be, Wk, Wq, Wv, Ws, bs, Kp, Qp, Vp, XSp);
    k_chunksum  <<<BB * NC, 256, 0, stream>>>(Kp, Vp, SKV, SK);
    k_prefix    <<<BB * DD * DD / 256, 256, 0, stream>>>(SKV, SK, S0, Z0, Sout, Zout);
    k_swrite    <<<BB * NC * 2, 256, 0, stream>>>(Kp, Vp, S0, Z0, Sout, Zout);
    k_numden_mlp<<<BB * NC, 256, 0, stream>>>(Kp, Qp, Vp, XSp, S0, Z0, Sout, Zout,
                                              W1, b1, W2, b2, outp);
}